// Round 5
// baseline (861.364 us; speedup 1.0000x reference)
//
#include <hip/hip_runtime.h>
#include <math.h>

#define D_TOT 480

typedef short bf16x8 __attribute__((ext_vector_type(8)));
typedef float f32x4 __attribute__((ext_vector_type(4)));

#define MFMA16(a, b, c) __builtin_amdgcn_mfma_f32_16x16x32_bf16((a), (b), (c), 0, 0, 0)

static __device__ __forceinline__ unsigned short f2bf(float x) {
  unsigned u = __float_as_uint(x);
  u += 0x7FFFu + ((u >> 16) & 1u);   // RNE (inputs finite)
  return (unsigned short)(u >> 16);
}
static __device__ __forceinline__ float bf2f(unsigned short v) {
  return __uint_as_float(((unsigned)v) << 16);
}
static __device__ __forceinline__ unsigned pk2(unsigned short a, unsigned short b) {
  return (unsigned)a | ((unsigned)b << 16);
}

// ---------------------------------------------------------------------------
// K0: Mtmp_b = (Wq_b . Wd_b . Wk_b^T) * scale_b (fp32), scale folds all norms:
//   scale_b = 1 / (m^2 * sqrt(1440*d)).
// ws fp32 layout: M0 [0,16384), M1 [16384,20480), M2 [20480,21504)
// ---------------------------------------------------------------------------
__global__ __launch_bounds__(256) void precompute_M(
    const float* __restrict__ Wq0, const float* __restrict__ Wq1, const float* __restrict__ Wq2,
    const float* __restrict__ Wk0, const float* __restrict__ Wk1, const float* __restrict__ Wk2,
    const float* __restrict__ Wd0, const float* __restrict__ Wd1, const float* __restrict__ Wd2,
    float* __restrict__ ws) {
  __shared__ float T[16 * 128];
  int b = blockIdx.x;
  const float *Wq, *Wk, *Wd;
  float* M;
  int m, deg, strip;
  if (b < 8)       { Wq = Wq0; Wk = Wk0; Wd = Wd0; M = ws;         m = 128; deg = 1; strip = b; }
  else if (b < 12) { Wq = Wq1; Wk = Wk1; Wd = Wd1; M = ws + 16384; m = 64;  deg = 3; strip = b - 8; }
  else if (b < 14) { Wq = Wq2; Wk = Wk2; Wd = Wd2; M = ws + 20480; m = 32;  deg = 5; strip = b - 12; }
  else return;
  int r0 = strip * 16;
  if (r0 >= m) return;
  float scale = 1.0f / ((float)m * (float)m * sqrtf(1440.0f * (float)deg));
  for (int idx = threadIdx.x; idx < 16 * m; idx += 256) {
    int r = idx / m, c = idx % m;
    float s = 0.f;
    for (int a = 0; a < m; ++a) s += Wq[(r0 + r) * m + a] * Wd[a * m + c];
    T[r * m + c] = s;
  }
  __syncthreads();
  for (int idx = threadIdx.x; idx < 16 * m; idx += 256) {
    int r = idx / m, j = idx % m;
    float s = 0.f;
    for (int c = 0; c < m; ++c) s += T[r * m + c] * Wk[j * m + c];
    M[(r0 + r) * m + j] = s * scale;
  }
}

// ---------------------------------------------------------------------------
// K0b: pack B = [M_b | Wv_b/sqrt(m)] (bf16) in per-MFMA-fragment layout.
// Fragment = 1 KB: elem (l,j) = B[k = kt*32+(l>>4)*8+j][c = ct*16+(l&15)].
// ---------------------------------------------------------------------------
__global__ __launch_bounds__(256) void pack_B(
    const float* __restrict__ Mtmp,
    const float* __restrict__ Wv0, const float* __restrict__ Wv1, const float* __restrict__ Wv2,
    unsigned short* __restrict__ Bp) {
  int idx = blockIdx.x * 256 + threadIdx.x;
  if (idx >= 43008) return;
  float val;
  if (idx < 32768) {
    int fragi = idx >> 9, rem = idx & 511;
    int l = rem >> 3, j = rem & 7;
    int ct = fragi >> 2, kt = fragi & 3;
    int k = kt * 32 + (l >> 4) * 8 + j;
    int c = ct * 16 + (l & 15);
    val = (c < 128) ? Mtmp[k * 128 + c] : Wv0[k * 128 + (c - 128)] * 0.08838834764831845f;
  } else if (idx < 40960) {
    int i1 = idx - 32768;
    int fragi = i1 >> 9, rem = i1 & 511;
    int l = rem >> 3, j = rem & 7;
    int ct = fragi >> 1, kt = fragi & 1;
    int k = kt * 32 + (l >> 4) * 8 + j;
    int c = ct * 16 + (l & 15);
    val = (c < 64) ? Mtmp[16384 + k * 64 + c] : Wv1[k * 64 + (c - 64)] * 0.125f;
  } else {
    int i2 = idx - 40960;
    int ct = i2 >> 9, rem = i2 & 511;
    int l = rem >> 3, j = rem & 7;
    int k = (l >> 4) * 8 + j;
    int c = ct * 16 + (l & 15);
    val = (c < 32) ? Mtmp[20480 + k * 32 + c] : Wv2[k * 32 + (c - 32)] * 0.17677669529663687f;
  }
  Bp[idx] = f2bf(val);
}

// ---------------------------------------------------------------------------
// K0c: gptr[g] = lower_bound(batch, g)  (batch sorted ascending)
// ---------------------------------------------------------------------------
__global__ __launch_bounds__(256) void build_gptr(
    const int* __restrict__ batch, int* __restrict__ gptr, int N, int G) {
  int g = blockIdx.x * 256 + threadIdx.x;
  if (g > G) return;
  int lo = 0, hi = N;
  while (lo < hi) {
    int mid = (lo + hi) >> 1;
    if (batch[mid] < g) lo = mid + 1; else hi = mid;
  }
  gptr[g] = lo;
}

// ---------------------------------------------------------------------------
// Fused kernel: ONE BLOCK PER GRAPH (batch sorted -> contiguous node range).
// 4 waves/block; wave handles 16-node tiles strided by 64. No atomics at all:
// register accumulation -> cross-wave LDS combine -> plain stores.
// A-frags load DIRECTLY from global (each element once per wave); LDS keeps
// only the natural bf16 tile for the logit x-dot (XOR swizzle (row&7)<<4).
// ---------------------------------------------------------------------------
__global__ __launch_bounds__(256, 2) void fused_graph_kernel(
    const float* __restrict__ f, const unsigned short* __restrict__ Bpack,
    const int* __restrict__ gptr, float* __restrict__ out, int N) {
  __shared__ __align__(16) unsigned short xs_all[4 * 8192];
  int t = threadIdx.x;
  int w = t >> 6, lane = t & 63;
  int q = lane >> 4, lm = lane & 15;
  char* xsb = (char*)(xs_all + w * 8192);
  unsigned swzlm = (unsigned)((lm & 7) << 4);

  int g = blockIdx.x;
  int s = gptr[g], e = gptr[g + 1];

  const bf16x8* B0f = (const bf16x8*)Bpack;
  const bf16x8* B1f = (const bf16x8*)(Bpack + 32768);
  const bf16x8* B2f = (const bf16x8*)(Bpack + 40960);

  float r0[8], r1[3][4], r2[5][2], naccw = 0.f;
#pragma unroll
  for (int i = 0; i < 8; ++i) r0[i] = 0.f;
#pragma unroll
  for (int d = 0; d < 3; ++d)
#pragma unroll
    for (int i = 0; i < 4; ++i) r1[d][i] = 0.f;
#pragma unroll
  for (int d = 0; d < 5; ++d)
#pragma unroll
    for (int i = 0; i < 2; ++i) r2[d][i] = 0.f;

  for (int nt = s + w * 16; nt < e; nt += 64) {
    int valid = min(16, e - nt);
    long rr = nt + (lm < valid ? lm : valid - 1);
    const float4* fr4 = reinterpret_cast<const float4*>(f + rr * 480);

    bf16x8 a0[4], a1[3][2], a2[5];

    // ---- irrep0: load 32 fp32 (k = ks*32+q*8 ..+8), build frags + LDS copy ----
#pragma unroll
    for (int ks = 0; ks < 4; ++ks) {
      float4 A = fr4[ks * 8 + 2 * q];
      float4 B = fr4[ks * 8 + 2 * q + 1];
      bf16x8 v;
      v[0] = (short)f2bf(A.x); v[1] = (short)f2bf(A.y);
      v[2] = (short)f2bf(A.z); v[3] = (short)f2bf(A.w);
      v[4] = (short)f2bf(B.x); v[5] = (short)f2bf(B.y);
      v[6] = (short)f2bf(B.z); v[7] = (short)f2bf(B.w);
      a0[ks] = v;
      uint4 pkv;
      pkv.x = pk2((unsigned short)v[0], (unsigned short)v[1]);
      pkv.y = pk2((unsigned short)v[2], (unsigned short)v[3]);
      pkv.z = pk2((unsigned short)v[4], (unsigned short)v[5]);
      pkv.w = pk2((unsigned short)v[6], (unsigned short)v[7]);
      *reinterpret_cast<uint4*>(xsb + lm * 1024 + (((unsigned)(ks * 64 + q * 16)) ^ swzlm)) = pkv;
    }

    // ---- irrep1: two 24-float windows (cols 128+96h+24q ..+24) ----
#pragma unroll
    for (int h = 0; h < 2; ++h) {
      unsigned short b[24];
#pragma unroll
      for (int i = 0; i < 6; ++i) {
        float4 x4 = fr4[32 + 24 * h + 6 * q + i];
        b[i * 4 + 0] = f2bf(x4.x); b[i * 4 + 1] = f2bf(x4.y);
        b[i * 4 + 2] = f2bf(x4.z); b[i * 4 + 3] = f2bf(x4.w);
      }
#pragma unroll
      for (int d = 0; d < 3; ++d) {
        bf16x8 v;
#pragma unroll
        for (int j = 0; j < 8; ++j) v[j] = (short)b[3 * j + d];
        a1[d][h] = v;
      }
#pragma unroll
      for (int i = 0; i < 3; ++i) {
        uint4 pkv;
        pkv.x = pk2(b[i * 8 + 0], b[i * 8 + 1]);
        pkv.y = pk2(b[i * 8 + 2], b[i * 8 + 3]);
        pkv.z = pk2(b[i * 8 + 4], b[i * 8 + 5]);
        pkv.w = pk2(b[i * 8 + 6], b[i * 8 + 7]);
        *reinterpret_cast<uint4*>(xsb + lm * 1024 +
            (((unsigned)(256 + 192 * h + 48 * q + 16 * i)) ^ swzlm)) = pkv;
      }
    }

    // ---- irrep2: one 40-float window (cols 320+40q ..+40) ----
    {
      unsigned short b[40];
#pragma unroll
      for (int i = 0; i < 10; ++i) {
        float4 x4 = fr4[80 + 10 * q + i];
        b[i * 4 + 0] = f2bf(x4.x); b[i * 4 + 1] = f2bf(x4.y);
        b[i * 4 + 2] = f2bf(x4.z); b[i * 4 + 3] = f2bf(x4.w);
      }
#pragma unroll
      for (int d = 0; d < 5; ++d) {
        bf16x8 v;
#pragma unroll
        for (int j = 0; j < 8; ++j) v[j] = (short)b[5 * j + d];
        a2[d] = v;
      }
#pragma unroll
      for (int i = 0; i < 5; ++i) {
        uint4 pkv;
        pkv.x = pk2(b[i * 8 + 0], b[i * 8 + 1]);
        pkv.y = pk2(b[i * 8 + 2], b[i * 8 + 3]);
        pkv.z = pk2(b[i * 8 + 4], b[i * 8 + 5]);
        pkv.w = pk2(b[i * 8 + 6], b[i * 8 + 7]);
        *reinterpret_cast<uint4*>(xsb + lm * 1024 +
            (((unsigned)(640 + 80 * q + 16 * i)) ^ swzlm)) = pkv;
      }
    }

    // x read in C-frag order: node = q*4+r, natural col c (same-wave LDS)
    auto ldx = [&](int node, int c) -> float {
      unsigned off = ((unsigned)(2 * c)) ^ ((unsigned)((node & 7) << 4));
      return bf2f(*reinterpret_cast<const unsigned short*>(xsb + node * 1024 + off));
    };

    // ---- u-phase: logits ----
    float pl0 = 0.f, pl1 = 0.f, pl2 = 0.f, pl3 = 0.f;
#pragma unroll
    for (int ct = 0; ct < 8; ++ct) {
      f32x4 u = {0.f, 0.f, 0.f, 0.f};
      u = MFMA16(a0[0], B0f[(ct * 4 + 0) * 64 + lane], u);
      u = MFMA16(a0[1], B0f[(ct * 4 + 1) * 64 + lane], u);
      u = MFMA16(a0[2], B0f[(ct * 4 + 2) * 64 + lane], u);
      u = MFMA16(a0[3], B0f[(ct * 4 + 3) * 64 + lane], u);
      int c = ct * 16 + lm;
      pl0 += u[0] * ldx(q * 4 + 0, c);
      pl1 += u[1] * ldx(q * 4 + 1, c);
      pl2 += u[2] * ldx(q * 4 + 2, c);
      pl3 += u[3] * ldx(q * 4 + 3, c);
    }
#pragma unroll
    for (int d = 0; d < 3; ++d)
#pragma unroll
      for (int ct = 0; ct < 4; ++ct) {
        f32x4 u = {0.f, 0.f, 0.f, 0.f};
        u = MFMA16(a1[d][0], B1f[(ct * 2 + 0) * 64 + lane], u);
        u = MFMA16(a1[d][1], B1f[(ct * 2 + 1) * 64 + lane], u);
        int c = 128 + 3 * (ct * 16 + lm) + d;
        pl0 += u[0] * ldx(q * 4 + 0, c);
        pl1 += u[1] * ldx(q * 4 + 1, c);
        pl2 += u[2] * ldx(q * 4 + 2, c);
        pl3 += u[3] * ldx(q * 4 + 3, c);
      }
#pragma unroll
    for (int d = 0; d < 5; ++d)
#pragma unroll
      for (int ct = 0; ct < 2; ++ct) {
        f32x4 u = {0.f, 0.f, 0.f, 0.f};
        u = MFMA16(a2[d], B2f[ct * 64 + lane], u);
        int c = 320 + 5 * (ct * 16 + lm) + d;
        pl0 += u[0] * ldx(q * 4 + 0, c);
        pl1 += u[1] * ldx(q * 4 + 1, c);
        pl2 += u[2] * ldx(q * 4 + 2, c);
        pl3 += u[3] * ldx(q * 4 + 3, c);
      }
#pragma unroll
    for (int off = 1; off < 16; off <<= 1) {
      pl0 += __shfl_xor(pl0, off);
      pl1 += __shfl_xor(pl1, off);
      pl2 += __shfl_xor(pl2, off);
      pl3 += __shfl_xor(pl3, off);
    }
    float w0 = (q * 4 + 0 < valid) ? __expf(pl0) : 0.f;
    float w1 = (q * 4 + 1 < valid) ? __expf(pl1) : 0.f;
    float w2 = (q * 4 + 2 < valid) ? __expf(pl2) : 0.f;
    float w3 = (q * 4 + 3 < valid) ? __expf(pl3) : 0.f;

    // ---- v-pass (whole tile is one graph: single weighted pass) ----
    if (lm == 0) naccw += w0 + w1 + w2 + w3;
#pragma unroll
    for (int ct = 0; ct < 8; ++ct) {
      f32x4 v = {0.f, 0.f, 0.f, 0.f};
      v = MFMA16(a0[0], B0f[((ct + 8) * 4 + 0) * 64 + lane], v);
      v = MFMA16(a0[1], B0f[((ct + 8) * 4 + 1) * 64 + lane], v);
      v = MFMA16(a0[2], B0f[((ct + 8) * 4 + 2) * 64 + lane], v);
      v = MFMA16(a0[3], B0f[((ct + 8) * 4 + 3) * 64 + lane], v);
      r0[ct] += w0 * v[0] + w1 * v[1] + w2 * v[2] + w3 * v[3];
    }
#pragma unroll
    for (int d = 0; d < 3; ++d)
#pragma unroll
      for (int ct = 0; ct < 4; ++ct) {
        f32x4 v = {0.f, 0.f, 0.f, 0.f};
        v = MFMA16(a1[d][0], B1f[((ct + 4) * 2 + 0) * 64 + lane], v);
        v = MFMA16(a1[d][1], B1f[((ct + 4) * 2 + 1) * 64 + lane], v);
        r1[d][ct] += w0 * v[0] + w1 * v[1] + w2 * v[2] + w3 * v[3];
      }
#pragma unroll
    for (int d = 0; d < 5; ++d)
#pragma unroll
      for (int ct = 0; ct < 2; ++ct) {
        f32x4 v = {0.f, 0.f, 0.f, 0.f};
        v = MFMA16(a2[d], B2f[(ct + 2) * 64 + lane], v);
        r2[d][ct] += w0 * v[0] + w1 * v[1] + w2 * v[2] + w3 * v[3];
      }
  }

  // ---- cross-wave combine (reuse LDS), then plain store ----
  __syncthreads();
  float* buf = (float*)xs_all;   // [4][496]
  auto wavered = [&](float s) -> float {
    s += __shfl_xor(s, 16);
    s += __shfl_xor(s, 32);
    return s;
  };
#pragma unroll
  for (int ct = 0; ct < 8; ++ct) {
    float sv = wavered(r0[ct]);
    if (lane < 16) buf[w * 496 + ct * 16 + lane] = sv;
  }
#pragma unroll
  for (int d = 0; d < 3; ++d)
#pragma unroll
    for (int ct = 0; ct < 4; ++ct) {
      float sv = wavered(r1[d][ct]);
      if (lane < 16) buf[w * 496 + 128 + 3 * (ct * 16 + lane) + d] = sv;
    }
#pragma unroll
  for (int d = 0; d < 5; ++d)
#pragma unroll
    for (int ct = 0; ct < 2; ++ct) {
      float sv = wavered(r2[d][ct]);
      if (lane < 16) buf[w * 496 + 320 + 5 * (ct * 16 + lane) + d] = sv;
    }
  {
    float sw = wavered(naccw);
    if (lane == 0) buf[w * 496 + 480] = sw;
  }
  __syncthreads();

  float nrm = buf[480] + buf[496 + 480] + buf[2 * 496 + 480] + buf[3 * 496 + 480];
  float inv = 1.0f / fmaxf(nrm, 1e-8f);
  for (int c = t; c < 480; c += 256) {
    float num = buf[c] + buf[496 + c] + buf[2 * 496 + c] + buf[3 * 496 + c];
    out[(size_t)g * 480 + c] = num * inv;
  }
}

extern "C" void kernel_launch(void* const* d_in, const int* in_sizes, int n_in,
                              void* d_out, int out_size, void* d_ws, size_t ws_size,
                              hipStream_t stream) {
  const float* f   = (const float*)d_in[0];
  const float* Wv0 = (const float*)d_in[7];
  const float* Wv1 = (const float*)d_in[8];
  const float* Wv2 = (const float*)d_in[9];
  const int* batch = (const int*)d_in[13];

  int N = in_sizes[0] / D_TOT;
  int G = out_size / D_TOT;

  // ws bytes: [0,86016) Mtmp fp32; [86016,172032) Bpack bf16; [172032,..) gptr
  float* Mtmp = (float*)d_ws;
  unsigned short* Bpack = (unsigned short*)((char*)d_ws + 86016);
  int* gptr = (int*)((char*)d_ws + 172032);

  build_gptr<<<(G + 256) / 256, 256, 0, stream>>>(batch, gptr, N, G);

  precompute_M<<<14, 256, 0, stream>>>(
      (const float*)d_in[1], (const float*)d_in[2], (const float*)d_in[3],
      (const float*)d_in[4], (const float*)d_in[5], (const float*)d_in[6],
      (const float*)d_in[10], (const float*)d_in[11], (const float*)d_in[12], Mtmp);

  pack_B<<<(43008 + 255) / 256, 256, 0, stream>>>(Mtmp, Wv0, Wv1, Wv2, Bpack);

  fused_graph_kernel<<<G, 256, 0, stream>>>(f, Bpack, gptr, (float*)d_out, N);
}